// Round 26
// baseline (387.715 us; speedup 1.0000x reference)
//
#include <hip/hip_runtime.h>
#include <hip/hip_fp16.h>
#include <hip/hip_cooperative_groups.h>

namespace cg = cooperative_groups;

#define NN 131072
#define NE 2097152
#define NT (NE + NN)        // edges + self loops
#define NTP (NE + 16 * NN)  // padded CSR capacity
#define NG 2048
#define NB 256              // coarse buckets (dst >> 9)
#define NPB 512             // nodes per bucket
#define CH 256              // chunks
#define ECH (NE / CH)       // 8192 edges per chunk
#define EPSV 1e-5f

typedef __fp16 half4v __attribute__((ext_vector_type(4)));
typedef float float4v __attribute__((ext_vector_type(4)));

// ---------------- CSR build: single cooperative kernel (5 phases, grid.sync between) ----------------
// grid = 256 blocks x 512 threads (8 waves/CU -> co-resident).
// A: per-chunk 256-bin histogram -> scanned[bucket][chunk] (bucket-major)
// B: global exclusive scan of scanned[65536]: row sums -> block0 scan -> row rescan
// C: stable packed scatter (block = chunk)
// D: fine pass (block = bucket): dinv, ninfo, srcs with self-loop + sentinel padding
__global__ __launch_bounds__(512) void k_csr(const int* __restrict__ esrc, const int* __restrict__ edst,
                                             int* __restrict__ scanned, int* __restrict__ rowsum,
                                             int* __restrict__ packed,
                                             int2* __restrict__ ninfo, float* __restrict__ dinv,
                                             int* __restrict__ srcs,
                                             float* __restrict__ statsZ,
                                             __half* __restrict__ sentA, __half* __restrict__ sentB) {
    cg::grid_group grid = cg::this_grid();
    __shared__ int shm[1536];
    int b = blockIdx.x, tid = threadIdx.x;

    // ---- Phase A: histogram of chunk b ----
    if (b == 0) {
        statsZ[tid] = 0.f; statsZ[tid + 512] = 0.f;
        if (tid < 64) {
            sentA[tid] = __float2half(0.f);
            sentB[tid] = __float2half(0.f);
        }
    }
    if (tid < NB) shm[tid] = 0;
    __syncthreads();
    {
        const int* d = edst + (long)b * ECH;
        for (int i = tid; i < ECH; i += 512) atomicAdd(&shm[d[i] >> 9], 1);
    }
    __syncthreads();
    if (tid < NB) scanned[tid * CH + b] = shm[tid];
    grid.sync();

    // ---- Phase B1: row sums (row b = bucket b) ----
    {
        int v = (tid < CH) ? scanned[b * CH + tid] : 0;
        if (tid < CH) shm[tid] = v;
        __syncthreads();
        for (int off = 128; off > 0; off >>= 1) {
            if (tid < off) shm[tid] += shm[tid + off];
            __syncthreads();
        }
        if (tid == 0) rowsum[b] = shm[0];
    }
    grid.sync();

    // ---- Phase B2: block 0 exclusive-scans the 256 row sums ----
    if (b == 0) {
        int rv = (tid < NB) ? rowsum[tid] : 0;
        if (tid < NB) shm[tid] = rv;
        __syncthreads();
        for (int off = 1; off < NB; off <<= 1) {
            int add = (tid < NB && tid >= off) ? shm[tid - off] : 0;
            __syncthreads();
            if (tid < NB) shm[tid] += add;
            __syncthreads();
        }
        if (tid < NB) rowsum[tid] = shm[tid] - rv;   // exclusive
    }
    grid.sync();

    // ---- Phase B3: per-row exclusive scan + row offset ----
    {
        int v = (tid < CH) ? scanned[b * CH + tid] : 0;
        if (tid < CH) shm[tid] = v;
        __syncthreads();
        for (int off = 1; off < CH; off <<= 1) {
            int add = (tid < CH && tid >= off) ? shm[tid - off] : 0;
            __syncthreads();
            if (tid < CH) shm[tid] += add;
            __syncthreads();
        }
        if (tid < CH) scanned[b * CH + tid] = shm[tid] - v + rowsum[b];
    }
    grid.sync();

    // ---- Phase C: stable scatter (block = chunk b) ----
    {
        if (tid < NB) shm[tid] = scanned[tid * CH + b];
        __syncthreads();
        const int* s = esrc + (long)b * ECH;
        const int* d = edst + (long)b * ECH;
        for (int i = tid; i < ECH; i += 512) {
            int dv = d[i], sv = s[i];
            int p = atomicAdd(&shm[dv >> 9], 1);
            packed[p] = sv | ((dv & 511) << 17);
        }
    }
    grid.sync();

    // ---- Phase D: fine pass (block = bucket b, 512 threads) ----
    {
        int* hist = shm;            // [512]
        int* sc = shm + 512;        // [512]
        int* cursor = shm + 1024;   // [512]
        int ebeg = scanned[b * CH];
        int eend = (b == NB - 1) ? NE : scanned[(b + 1) * CH];
        hist[tid] = 0;
        __syncthreads();
        for (int e = ebeg + tid; e < eend; e += NPB)
            atomicAdd(&hist[packed[e] >> 17], 1);
        __syncthreads();
        int cnt = hist[tid] + 1;                      // +1 self loop
        int pc = (cnt + 15) & ~15;                    // pad to multiple of 16
        sc[tid] = pc;
        __syncthreads();
        for (int off = 1; off < NPB; off <<= 1) {
            int v = (tid >= off) ? sc[tid - off] : 0;
            __syncthreads();
            sc[tid] += v;
            __syncthreads();
        }
        int rbase = ebeg + b * 8192;                  // bucket's padded region base
        int base = rbase + sc[tid] - pc;              // exclusive scan
        int n = (b << 9) | tid;
        ninfo[n] = make_int2(base, pc);
        dinv[n] = rsqrtf((float)cnt);
        srcs[base] = n;                               // self loop first
        cursor[tid] = base + 1;
        __syncthreads();
        for (int e = ebeg + tid; e < eend; e += NPB) {
            int p = packed[e];
            int pos = atomicAdd(&cursor[p >> 17], 1);
            srcs[pos] = p & 131071;
        }
        __syncthreads();
        for (int q = base + cnt; q < base + pc; ++q) srcs[q] = NN;  // sentinel padding
    }
}

// ---------------- gemm1 (MFMA 16x16x16 f16): [64 x 128] @ [128 x 64] -> fp16 * dinv[row] ----------------
__global__ __launch_bounds__(256) void k_gemm1(const float* __restrict__ A,
                                               const float* __restrict__ W,
                                               const float* __restrict__ dinv,
                                               __half* __restrict__ out) {
    __shared__ __fp16 as_[64 * 132];
    __shared__ __fp16 ws_[64 * 132];
    int tid = threadIdx.x;
    long row0 = (long)blockIdx.x * 64;
    const float4v* Ag = (const float4v*)(A + row0 * 128);
#pragma unroll
    for (int i = 0; i < 8; ++i) {
        int flat = tid + i * 256;          // unit: 4 floats
        int row = flat >> 5, k4 = flat & 31;
        float4v v = Ag[flat];
        half4v h = {(__fp16)v.x, (__fp16)v.y, (__fp16)v.z, (__fp16)v.w};
        *(half4v*)&as_[row * 132 + k4 * 4] = h;
    }
#pragma unroll
    for (int i = 0; i < 32; ++i) {
        int flat = tid + i * 256;
        int k = flat >> 6, n = flat & 63;
        ws_[n * 132 + k] = (__fp16)W[flat];
    }
    __syncthreads();
    int w = tid >> 6, l = tid & 63;
    int lr = l & 15, lg = l >> 4;
    float4v acc[4] = {};
    for (int k0 = 0; k0 < 128; k0 += 16) {
        half4v a = *(const half4v*)&as_[(w * 16 + lr) * 132 + k0 + lg * 4];
#pragma unroll
        for (int t4 = 0; t4 < 4; ++t4) {
            half4v b = *(const half4v*)&ws_[(t4 * 16 + lr) * 132 + k0 + lg * 4];
            acc[t4] = __builtin_amdgcn_mfma_f32_16x16x16f16(a, b, acc[t4], 0, 0, 0);
        }
    }
    float dv[4];
#pragma unroll
    for (int r = 0; r < 4; ++r) dv[r] = dinv[row0 + w * 16 + lg * 4 + r];
#pragma unroll
    for (int t4 = 0; t4 < 4; ++t4)
#pragma unroll
        for (int r = 0; r < 4; ++r) {
            long row = row0 + w * 16 + lg * 4 + r;
            out[row * 64 + t4 * 16 + lr] = __float2half(acc[t4][r] * dv[r]);
        }
}

// ---------------- gemm2 (MFMA v2): fp16 [64 x 64] @ f32 [64 x 128] -> fp16 + conflict-free BN stats ----------------
__global__ __launch_bounds__(256) void k_gemm2(const __half* __restrict__ A,
                                               const float* __restrict__ W,
                                               __half* __restrict__ out,
                                               float* __restrict__ pS, float* __restrict__ pQ) {
    __shared__ __fp16 as_[64 * 68];
    __shared__ __fp16 ws_[128 * 68];
    __shared__ float redS[16][128], redQ[16][128];
    int tid = threadIdx.x;
    long row0 = (long)blockIdx.x * 64;
    const int4* Ag = (const int4*)(A + row0 * 64);
#pragma unroll
    for (int i = 0; i < 2; ++i) {
        int flat8 = tid + i * 256;         // unit: 8 halves
        int row = flat8 >> 3, h8 = flat8 & 7;
        int4 v = Ag[flat8];
        *(half4v*)&as_[row * 68 + h8 * 8]     = *(half4v*)&v;
        *(half4v*)&as_[row * 68 + h8 * 8 + 4] = *((half4v*)&v + 1);
    }
#pragma unroll
    for (int i = 0; i < 32; ++i) {
        int flat = tid + i * 256;
        int k = flat >> 7, n = flat & 127;
        ws_[n * 68 + k] = (__fp16)W[flat];
    }
    __syncthreads();
    int w = tid >> 6, l = tid & 63;
    int lr = l & 15, lg = l >> 4;
    float4v acc[8] = {};
    for (int k0 = 0; k0 < 64; k0 += 16) {
        half4v a = *(const half4v*)&as_[(w * 16 + lr) * 68 + k0 + lg * 4];
#pragma unroll
        for (int t4 = 0; t4 < 8; ++t4) {
            half4v b = *(const half4v*)&ws_[(t4 * 16 + lr) * 68 + k0 + lg * 4];
            acc[t4] = __builtin_amdgcn_mfma_f32_16x16x16f16(a, b, acc[t4], 0, 0, 0);
        }
    }
    int band = w * 4 + lg;
#pragma unroll
    for (int t4 = 0; t4 < 8; ++t4) {
        float cs = acc[t4][0] + acc[t4][1] + acc[t4][2] + acc[t4][3];
        float cq = acc[t4][0] * acc[t4][0] + acc[t4][1] * acc[t4][1] +
                   acc[t4][2] * acc[t4][2] + acc[t4][3] * acc[t4][3];
        redS[band][t4 * 16 + lr] = cs;
        redQ[band][t4 * 16 + lr] = cq;
    }
#pragma unroll
    for (int t4 = 0; t4 < 8; ++t4)
#pragma unroll
        for (int r = 0; r < 4; ++r) {
            long row = row0 + w * 16 + lg * 4 + r;
            out[row * 128 + t4 * 16 + lr] = __float2half(acc[t4][r]);
        }
    __syncthreads();
    if (tid < 128) {
        float s = 0.f, q = 0.f;
#pragma unroll
        for (int t = 0; t < 16; ++t) { s += redS[t][tid]; q += redQ[t][tid]; }
        pS[blockIdx.x * 128 + tid] = s;
        pQ[blockIdx.x * 128 + tid] = q;
    }
}

__global__ void k_redstats(const float* __restrict__ pS, const float* __restrict__ pQ,
                           float* __restrict__ sums, float* __restrict__ sqs) {
    int c = threadIdx.x;
    int rbeg = blockIdx.x * 32;
    float a = 0.f;
    if (c < 128) {
        for (int r = 0; r < 32; ++r) a += pS[(rbeg + r) * 128 + c];
        atomicAdd(&sums[c], a);
    } else {
        int cc = c - 128;
        for (int r = 0; r < 32; ++r) a += pQ[(rbeg + r) * 128 + cc];
        atomicAdd(&sqs[cc], a);
    }
}

// ---------------- CSR aggregation: feat pre-scaled by dinv[src]; padded edge lists ----------------
// 32-edge main loop: both srcs index vectors issued up front -> 16 independent feat-load
// instructions in flight per wave; 16-edge tail.  (R20-proven version)
__global__ __launch_bounds__(256) void k_agg(const __half2* __restrict__ feat2,
                                             const int2* __restrict__ ninfo,
                                             const int* __restrict__ srcs,
                                             const float* __restrict__ dinv,
                                             __half2* __restrict__ out) {
    int wid = (blockIdx.x * 256 + threadIdx.x) >> 6;   // one wave per dst node
    int lane = threadIdx.x & 63;
    int hi = lane >> 5;
    int c = lane & 31;
    int2 ni = ninfo[wid];                              // broadcast 8B load
    int e0 = ni.x, pd = ni.y;
    int eend = e0 + pd;
    float ax = 0.f, ay = 0.f;
    int e = e0;
    for (; e + 32 <= eend; e += 32) {
        int i0 = srcs[e + hi * 8 + (c & 7)];           // 16 consecutive ints
        int i1 = srcs[e + 16 + hi * 8 + (c & 7)];      // next 16 (issued before any feat load)
#pragma unroll
        for (int j = 0; j < 8; ++j) {
            int s = __shfl(i0, j, 32);
            float2 f = __half22float2(feat2[(long)s * 32 + c]);
            ax += f.x;
            ay += f.y;
        }
#pragma unroll
        for (int j = 0; j < 8; ++j) {
            int s = __shfl(i1, j, 32);
            float2 f = __half22float2(feat2[(long)s * 32 + c]);
            ax += f.x;
            ay += f.y;
        }
    }
    if (e < eend) {                                    // exactly 16 remain
        int i0 = srcs[e + hi * 8 + (c & 7)];
#pragma unroll
        for (int j = 0; j < 8; ++j) {
            int s = __shfl(i0, j, 32);
            float2 f = __half22float2(feat2[(long)s * 32 + c]);
            ax += f.x;
            ay += f.y;
        }
    }
    ax += __shfl_xor(ax, 32);
    ay += __shfl_xor(ay, 32);
    if (hi == 0) {
        float dn = dinv[wid];
        out[(long)wid * 32 + c] = __floats2half2_rn(ax * dn, ay * dn);
    }
}

// ---------------- BN1 stats over fp16 h1 ----------------
__global__ __launch_bounds__(256) void k_stats64h(const __half2* __restrict__ h2,
                                                  float* __restrict__ sums, float* __restrict__ sqs) {
    __shared__ float sx[256], sy[256], qx[256], qy[256];
    int tid = threadIdx.x;
    int c = tid & 31, rg = tid >> 5;
    long row0 = (long)blockIdx.x * 1024;
    float ax = 0.f, ay = 0.f, bx = 0.f, by = 0.f;
    for (int i = rg; i < 1024; i += 8) {
        float2 f = __half22float2(h2[(row0 + i) * 32 + c]);
        ax += f.x; ay += f.y; bx += f.x * f.x; by += f.y * f.y;
    }
    sx[tid] = ax; sy[tid] = ay; qx[tid] = bx; qy[tid] = by;
    __syncthreads();
    if (tid < 32) {
        float tax = 0.f, tay = 0.f, tbx = 0.f, tby = 0.f;
#pragma unroll
        for (int g = 0; g < 8; ++g) {
            tax += sx[g * 32 + tid]; tay += sy[g * 32 + tid];
            tbx += qx[g * 32 + tid]; tby += qy[g * 32 + tid];
        }
        atomicAdd(&sums[2 * tid], tax); atomicAdd(&sums[2 * tid + 1], tay);
        atomicAdd(&sqs[2 * tid], tbx);  atomicAdd(&sqs[2 * tid + 1], tby);
    }
}

// BN1 prep (inlined per block) + apply + leaky + dinv[row] pre-scale, fp16 in/out
__global__ __launch_bounds__(256) void k_apply1h(const __half* __restrict__ h,
                                                 const float* __restrict__ sums,
                                                 const float* __restrict__ sqs,
                                                 const float* __restrict__ gamma,
                                                 const float* __restrict__ beta,
                                                 const float* __restrict__ dinv,
                                                 __half* __restrict__ out) {
    __shared__ float sc_[64], sh_[64];
    int tid = threadIdx.x;
    if (tid < 64) {
        const float invN = 1.0f / (float)NN;
        float mean = sums[tid] * invN;
        float var = sqs[tid] * invN - mean * mean;
        float inv = rsqrtf(var + EPSV);
        float s = gamma[tid] * inv;
        sc_[tid] = s;
        sh_[tid] = beta[tid] - mean * s;
    }
    __syncthreads();
    long idx = (long)blockIdx.x * 256 + tid;           // unit: 8 halves
    int row = (int)(idx >> 3);
    int cb = (int)(idx & 7) * 8;
    float dv = dinv[row];
    int4 v = ((const int4*)h)[idx];
    __half2* hp = (__half2*)&v;
    int4 o;
    __half2* op = (__half2*)&o;
#pragma unroll
    for (int j = 0; j < 4; ++j) {
        float2 f = __half22float2(hp[j]);
        float y0 = fmaf(f.x, sc_[cb + 2 * j], sh_[cb + 2 * j]);
        float y1 = fmaf(f.y, sc_[cb + 2 * j + 1], sh_[cb + 2 * j + 1]);
        y0 = y0 > 0.f ? y0 : 0.01f * y0;
        y1 = y1 > 0.f ? y1 : 0.01f * y1;
        op[j] = __floats2half2_rn(y0 * dv, y1 * dv);
    }
    ((int4*)out)[idx] = o;
}

// ---------------- pooling: BN2 prep (inlined) + graph range search (inlined) + BN2+leaky + head ----------------
__global__ __launch_bounds__(256) void k_pool(const __half* __restrict__ h,
                                              const int* __restrict__ batch,
                                              const float* __restrict__ sums,
                                              const float* __restrict__ sqs,
                                              const float* __restrict__ gamma,
                                              const float* __restrict__ beta,
                                              const float* __restrict__ Wo,
                                              const float* __restrict__ bo,
                                              float* __restrict__ out) {
    __shared__ float accx[4][64], accy[4][64];
    __shared__ float sc_[128], sh_[128];
    __shared__ int range[2];
    int g = blockIdx.x;
    int tid = threadIdx.x;
    int wv = tid >> 6, lane = tid & 63;
    if (tid < 128) {
        const float invN = 1.0f / (float)NN;
        float mean = sums[tid] * invN;
        float var = sqs[tid] * invN - mean * mean;
        float inv = rsqrtf(var + EPSV);
        float s = gamma[tid] * inv;
        sc_[tid] = s;
        sh_[tid] = beta[tid] - mean * s;
    }
    if (tid < 2) {                                     // binary search for lower bounds of g and g+1
        int target = g + tid;
        int lo = 0, hi = NN;
        while (lo < hi) {
            int mid = (lo + hi) >> 1;
            if (batch[mid] < target) lo = mid + 1; else hi = mid;
        }
        range[tid] = lo;
    }
    __syncthreads();
    int beg = range[0], cnt = range[1] - range[0];
    float sc0 = sc_[2 * lane], sc1 = sc_[2 * lane + 1];
    float sh0 = sh_[2 * lane], sh1 = sh_[2 * lane + 1];
    float a0 = 0.f, a1 = 0.f;
    for (int i = wv; i < cnt; i += 4) {
        __half2 v = ((const __half2*)(h + (long)(beg + i) * 128))[lane];
        float2 f = __half22float2(v);
        float y0 = fmaf(f.x, sc0, sh0); y0 = y0 > 0.f ? y0 : 0.01f * y0;
        float y1 = fmaf(f.y, sc1, sh1); y1 = y1 > 0.f ? y1 : 0.01f * y1;
        a0 += y0; a1 += y1;
    }
    accx[wv][lane] = a0;
    accy[wv][lane] = a1;
    __syncthreads();
    if (wv == 0) {
        a0 = accx[0][lane] + accx[1][lane] + accx[2][lane] + accx[3][lane];
        a1 = accy[0][lane] + accy[1][lane] + accy[2][lane] + accy[3][lane];
        float v = a0 * Wo[2 * lane] + a1 * Wo[2 * lane + 1];
        v /= fmaxf((float)cnt, 1.f);
#pragma unroll
        for (int m = 32; m; m >>= 1) v += __shfl_xor(v, m);
        if (lane == 0) out[g] = v + bo[0];
    }
}

extern "C" void kernel_launch(void* const* d_in, const int* in_sizes, int n_in,
                              void* d_out, int out_size, void* d_ws, size_t ws_size,
                              hipStream_t stream) {
    const float* x    = (const float*)d_in[0];
    const int* ei     = (const int*)d_in[1];
    const int* batch  = (const int*)d_in[2];
    const float* W1   = (const float*)d_in[3];
    const float* g1   = (const float*)d_in[5];
    const float* be1  = (const float*)d_in[6];
    const float* W2   = (const float*)d_in[7];
    const float* g2   = (const float*)d_in[9];
    const float* be2  = (const float*)d_in[10];
    const float* Wo   = (const float*)d_in[11];
    const float* bo   = (const float*)d_in[12];
    float* out = (float*)d_out;

    const int* esrc = ei;
    const int* edst = ei + NE;

    // ---- workspace layout ----
    __half* h2h = (__half*)d_ws;                   // [NN,128] half (33.5MB); alias: packed
    __half* bufA = h2h + (size_t)NN * 128;         // [NN+1,64] half; alias: scanned
    __half* bufB = bufA + (size_t)(NN + 1) * 64;   // [NN+1,64] half
    float* dinv = (float*)(bufB + (size_t)(NN + 1) * 64); // [NN]
    float* stats = dinv + NN;                      // 1024 floats (zeroed by k_csr block 0)
    float* sums1 = stats,        *sqs1 = stats + 64;
    float* sums2 = stats + 128,  *sqs2 = stats + 256;
    int2* ninfo = (int2*)(stats + 1024);           // [NN]
    int* srcs   = (int*)(ninfo + NN);              // [NTP]
    int* rowsum = srcs + NTP;                      // 256
    float* pS   = (float*)(rowsum + 256 + 8);      // [2048][128]
    float* pQ   = pS + 2048 * 128;                 // [2048][128]
    // temporal aliases
    int* scanned = (int*)bufA;                     // [NB][CH]  (consumed before gemm1 writes bufA)
    int* packed  = (int*)h2h;                      // [NE]      (consumed before gemm2 writes h2h)
    __half* sentA = bufA + (size_t)NN * 64;        // sentinel rows (zeroed by k_csr)
    __half* sentB = bufB + (size_t)NN * 64;

    // ---- CSR build: one cooperative kernel (histogram -> scan -> scatter -> fine) ----
    {
        void* args[] = {(void*)&esrc, (void*)&edst, (void*)&scanned, (void*)&rowsum,
                        (void*)&packed, (void*)&ninfo, (void*)&dinv, (void*)&srcs,
                        (void*)&stats, (void*)&sentA, (void*)&sentB};
        hipLaunchCooperativeKernel((const void*)k_csr, dim3(NB), dim3(512), args, 0, stream);
    }

    // layer 1: xw1' = (x @ W1) * dinv[row]  (fp16, MFMA)
    k_gemm1<<<NN / 64, 256, 0, stream>>>(x, W1, dinv, bufA);
    k_agg<<<NN / 4, 256, 0, stream>>>((const __half2*)bufA, ninfo, srcs, dinv, (__half2*)bufB);
    k_stats64h<<<NN / 1024, 256, 0, stream>>>((const __half2*)bufB, sums1, sqs1);
    k_apply1h<<<NN * 64 / 8 / 256, 256, 0, stream>>>(bufB, sums1, sqs1, g1, be1, dinv, bufB);

    // layer 2: agg in 64ch, then gemm2 (MFMA v2, +fused conflict-free BN2 stats)
    k_agg<<<NN / 4, 256, 0, stream>>>((const __half2*)bufB, ninfo, srcs, dinv, (__half2*)bufA);
    k_gemm2<<<NN / 64, 256, 0, stream>>>(bufA, W2, h2h, pS, pQ);
    k_redstats<<<64, 256, 0, stream>>>(pS, pQ, sums2, sqs2);

    // pooling (+BN2 prep + range search + leaky fused) + head: one block per graph
    k_pool<<<NG, 256, 0, stream>>>(h2h, batch, sums2, sqs2, g2, be2, Wo, bo, out);
}

// Round 27
// 234.252 us; speedup vs baseline: 1.6551x; 1.6551x over previous
//
#include <hip/hip_runtime.h>
#include <hip/hip_fp16.h>

#define NN 131072
#define NE 2097152
#define NT (NE + NN)        // edges + self loops
#define NTP (NE + 16 * NN)  // padded CSR capacity
#define NG 2048
#define NB 256              // coarse buckets (dst >> 9)
#define NPB 512             // nodes per bucket
#define CH 256              // chunks
#define ECH (NE / CH)       // 8192 edges per chunk
#define EPSV 1e-5f

typedef __fp16 half4v __attribute__((ext_vector_type(4)));
typedef float float4v __attribute__((ext_vector_type(4)));

// ---------------- scan helper (per-1024-block exclusive scan + block sums) ----------------
__global__ void k_scan1(const int* __restrict__ in, int* __restrict__ out,
                        int* __restrict__ bsums, int n) {
    __shared__ int tmp[1024];
    int t = threadIdx.x;
    int gid = blockIdx.x * 1024 + t;
    int v = (gid < n) ? in[gid] : 0;
    tmp[t] = v;
    __syncthreads();
    for (int off = 1; off < 1024; off <<= 1) {
        int add = (t >= off) ? tmp[t - off] : 0;
        __syncthreads();
        tmp[t] += add;
        __syncthreads();
    }
    if (gid < n) out[gid] = tmp[t] - v;       // exclusive (within block)
    if (t == 1023) bsums[blockIdx.x] = tmp[t];
}

// ---------------- CSR build: stable two-level counting sort ----------------
// chist (512 thr): writes bucket-major histogram; block 0 zeroes stats + sentinel rows.
__global__ __launch_bounds__(512) void k_chist(const int* __restrict__ dst, int* __restrict__ ghist_t,
                                               float* __restrict__ statsZ,
                                               __half* __restrict__ sentA, __half* __restrict__ sentB) {
    __shared__ int h[NB];
    int c = blockIdx.x, tid = threadIdx.x;
    if (c == 0) {
        statsZ[tid] = 0.f; statsZ[tid + 512] = 0.f;
        if (tid < 64) {
            sentA[tid] = __float2half(0.f);
            sentB[tid] = __float2half(0.f);
        }
    }
    if (tid < NB) h[tid] = 0;
    __syncthreads();
    const int* d = dst + (long)c * ECH;
    for (int i = tid; i < ECH; i += 512) atomicAdd(&h[d[i] >> 9], 1);
    __syncthreads();
    if (tid < NB) ghist_t[tid * CH + c] = h[tid];   // bucket-major
}
// scatter (512 thr): block = chunk; pack src (17b) | (dst & 511) << 17
__global__ __launch_bounds__(512) void k_cscatter(const int* __restrict__ src, const int* __restrict__ dst,
                                                  const int* __restrict__ scanned,
                                                  const int* __restrict__ bsums2,
                                                  int* __restrict__ packed) {
    __shared__ int cur[NB];
    int c = blockIdx.x, tid = threadIdx.x;
    if (tid < NB) {
        int idx = tid * CH + c;
        cur[tid] = scanned[idx] + bsums2[idx >> 10];
    }
    __syncthreads();
    const int* s = src + (long)c * ECH;
    const int* d = dst + (long)c * ECH;
    for (int i = tid; i < ECH; i += 512) {
        int dv = d[i], sv = s[i];
        int p = atomicAdd(&cur[dv >> 9], 1);
        packed[p] = sv | ((dv & 511) << 17);
    }
}
// fine pass (1024 thr): block = bucket (512 nodes). Emits dinv, ninfo(start,paddedDeg),
// srcs with self loop first + sentinel (NN) padding to a multiple of 16.
__global__ __launch_bounds__(1024) void k_fine(const int* __restrict__ packed,
                                               const int* __restrict__ scanned,
                                               const int* __restrict__ bsums2,
                                               int2* __restrict__ ninfo, float* __restrict__ dinv,
                                               int* __restrict__ srcs) {
    __shared__ int hist[NPB], sc[NPB], cursor[NPB];
    int b = blockIdx.x, tid = threadIdx.x;
    int ebeg = scanned[b * CH] + bsums2[(b * CH) >> 10];
    int eend = (b == NB - 1) ? NE : (scanned[(b + 1) * CH] + bsums2[((b + 1) * CH) >> 10]);
    if (tid < NPB) hist[tid] = 0;
    __syncthreads();
    for (int e = ebeg + tid; e < eend; e += 1024)
        atomicAdd(&hist[packed[e] >> 17], 1);
    __syncthreads();
    int cnt = 0, pc = 0;
    if (tid < NPB) {
        cnt = hist[tid] + 1;                      // +1 self loop
        pc = (cnt + 15) & ~15;                    // pad to multiple of 16
        sc[tid] = pc;
    }
    __syncthreads();
    for (int off = 1; off < NPB; off <<= 1) {
        int v = (tid < NPB && tid >= off) ? sc[tid - off] : 0;
        __syncthreads();
        if (tid < NPB) sc[tid] += v;
        __syncthreads();
    }
    int rbase = ebeg + b * 8192;                  // bucket's padded region base
    if (tid < NPB) {
        int base = rbase + sc[tid] - pc;          // exclusive scan
        int n = (b << 9) | tid;
        ninfo[n] = make_int2(base, pc);
        dinv[n] = rsqrtf((float)cnt);
        srcs[base] = n;                           // self loop first
        cursor[tid] = base + 1;
    }
    __syncthreads();
    for (int e = ebeg + tid; e < eend; e += 1024) {
        int p = packed[e];
        int pos = atomicAdd(&cursor[p >> 17], 1);
        srcs[pos] = p & 131071;
    }
    __syncthreads();
    if (tid < NPB) {
        int base = rbase + sc[tid] - pc;
        for (int q = base + cnt; q < base + pc; ++q) srcs[q] = NN;  // sentinel padding
    }
}

// ---------------- gemm1 (MFMA 16x16x16 f16): [64 x 128] @ [128 x 64] -> fp16 * dinv[row] ----------------
__global__ __launch_bounds__(256) void k_gemm1(const float* __restrict__ A,
                                               const float* __restrict__ W,
                                               const float* __restrict__ dinv,
                                               __half* __restrict__ out) {
    __shared__ __fp16 as_[64 * 132];
    __shared__ __fp16 ws_[64 * 132];
    int tid = threadIdx.x;
    long row0 = (long)blockIdx.x * 64;
    const float4v* Ag = (const float4v*)(A + row0 * 128);
#pragma unroll
    for (int i = 0; i < 8; ++i) {
        int flat = tid + i * 256;          // unit: 4 floats
        int row = flat >> 5, k4 = flat & 31;
        float4v v = Ag[flat];
        half4v h = {(__fp16)v.x, (__fp16)v.y, (__fp16)v.z, (__fp16)v.w};
        *(half4v*)&as_[row * 132 + k4 * 4] = h;
    }
#pragma unroll
    for (int i = 0; i < 32; ++i) {
        int flat = tid + i * 256;
        int k = flat >> 6, n = flat & 63;
        ws_[n * 132 + k] = (__fp16)W[flat];
    }
    __syncthreads();
    int w = tid >> 6, l = tid & 63;
    int lr = l & 15, lg = l >> 4;
    float4v acc[4] = {};
    for (int k0 = 0; k0 < 128; k0 += 16) {
        half4v a = *(const half4v*)&as_[(w * 16 + lr) * 132 + k0 + lg * 4];
#pragma unroll
        for (int t4 = 0; t4 < 4; ++t4) {
            half4v b = *(const half4v*)&ws_[(t4 * 16 + lr) * 132 + k0 + lg * 4];
            acc[t4] = __builtin_amdgcn_mfma_f32_16x16x16f16(a, b, acc[t4], 0, 0, 0);
        }
    }
    float dv[4];
#pragma unroll
    for (int r = 0; r < 4; ++r) dv[r] = dinv[row0 + w * 16 + lg * 4 + r];
#pragma unroll
    for (int t4 = 0; t4 < 4; ++t4)
#pragma unroll
        for (int r = 0; r < 4; ++r) {
            long row = row0 + w * 16 + lg * 4 + r;
            out[row * 64 + t4 * 16 + lr] = __float2half(acc[t4][r] * dv[r]);
        }
}

// ---------------- gemm2 (MFMA v2): fp16 [64 x 64] @ f32 [64 x 128] -> fp16 + conflict-free BN stats ----------------
__global__ __launch_bounds__(256) void k_gemm2(const __half* __restrict__ A,
                                               const float* __restrict__ W,
                                               __half* __restrict__ out,
                                               float* __restrict__ pS, float* __restrict__ pQ) {
    __shared__ __fp16 as_[64 * 68];
    __shared__ __fp16 ws_[128 * 68];
    __shared__ float redS[16][128], redQ[16][128];
    int tid = threadIdx.x;
    long row0 = (long)blockIdx.x * 64;
    const int4* Ag = (const int4*)(A + row0 * 64);
#pragma unroll
    for (int i = 0; i < 2; ++i) {
        int flat8 = tid + i * 256;         // unit: 8 halves
        int row = flat8 >> 3, h8 = flat8 & 7;
        int4 v = Ag[flat8];
        *(half4v*)&as_[row * 68 + h8 * 8]     = *(half4v*)&v;
        *(half4v*)&as_[row * 68 + h8 * 8 + 4] = *((half4v*)&v + 1);
    }
#pragma unroll
    for (int i = 0; i < 32; ++i) {
        int flat = tid + i * 256;
        int k = flat >> 7, n = flat & 127;
        ws_[n * 68 + k] = (__fp16)W[flat];
    }
    __syncthreads();
    int w = tid >> 6, l = tid & 63;
    int lr = l & 15, lg = l >> 4;
    float4v acc[8] = {};
    for (int k0 = 0; k0 < 64; k0 += 16) {
        half4v a = *(const half4v*)&as_[(w * 16 + lr) * 68 + k0 + lg * 4];
#pragma unroll
        for (int t4 = 0; t4 < 8; ++t4) {
            half4v b = *(const half4v*)&ws_[(t4 * 16 + lr) * 68 + k0 + lg * 4];
            acc[t4] = __builtin_amdgcn_mfma_f32_16x16x16f16(a, b, acc[t4], 0, 0, 0);
        }
    }
    int band = w * 4 + lg;
#pragma unroll
    for (int t4 = 0; t4 < 8; ++t4) {
        float cs = acc[t4][0] + acc[t4][1] + acc[t4][2] + acc[t4][3];
        float cq = acc[t4][0] * acc[t4][0] + acc[t4][1] * acc[t4][1] +
                   acc[t4][2] * acc[t4][2] + acc[t4][3] * acc[t4][3];
        redS[band][t4 * 16 + lr] = cs;
        redQ[band][t4 * 16 + lr] = cq;
    }
#pragma unroll
    for (int t4 = 0; t4 < 8; ++t4)
#pragma unroll
        for (int r = 0; r < 4; ++r) {
            long row = row0 + w * 16 + lg * 4 + r;
            out[row * 128 + t4 * 16 + lr] = __float2half(acc[t4][r]);
        }
    __syncthreads();
    if (tid < 128) {
        float s = 0.f, q = 0.f;
#pragma unroll
        for (int t = 0; t < 16; ++t) { s += redS[t][tid]; q += redQ[t][tid]; }
        pS[blockIdx.x * 128 + tid] = s;
        pQ[blockIdx.x * 128 + tid] = q;
    }
}

__global__ void k_redstats(const float* __restrict__ pS, const float* __restrict__ pQ,
                           float* __restrict__ sums, float* __restrict__ sqs) {
    int c = threadIdx.x;
    int rbeg = blockIdx.x * 32;
    float a = 0.f;
    if (c < 128) {
        for (int r = 0; r < 32; ++r) a += pS[(rbeg + r) * 128 + c];
        atomicAdd(&sums[c], a);
    } else {
        int cc = c - 128;
        for (int r = 0; r < 32; ++r) a += pQ[(rbeg + r) * 128 + cc];
        atomicAdd(&sqs[cc], a);
    }
}

// ---------------- CSR aggregation: feat pre-scaled by dinv[src]; padded edge lists ----------------
// 32-edge main loop: both srcs index vectors issued up front -> 16 independent feat-load
// instructions in flight per wave; 16-edge tail.  (R20-proven version)
__global__ __launch_bounds__(256) void k_agg(const __half2* __restrict__ feat2,
                                             const int2* __restrict__ ninfo,
                                             const int* __restrict__ srcs,
                                             const float* __restrict__ dinv,
                                             __half2* __restrict__ out) {
    int wid = (blockIdx.x * 256 + threadIdx.x) >> 6;   // one wave per dst node
    int lane = threadIdx.x & 63;
    int hi = lane >> 5;
    int c = lane & 31;
    int2 ni = ninfo[wid];                              // broadcast 8B load
    int e0 = ni.x, pd = ni.y;
    int eend = e0 + pd;
    float ax = 0.f, ay = 0.f;
    int e = e0;
    for (; e + 32 <= eend; e += 32) {
        int i0 = srcs[e + hi * 8 + (c & 7)];           // 16 consecutive ints
        int i1 = srcs[e + 16 + hi * 8 + (c & 7)];      // next 16 (issued before any feat load)
#pragma unroll
        for (int j = 0; j < 8; ++j) {
            int s = __shfl(i0, j, 32);
            float2 f = __half22float2(feat2[(long)s * 32 + c]);
            ax += f.x;
            ay += f.y;
        }
#pragma unroll
        for (int j = 0; j < 8; ++j) {
            int s = __shfl(i1, j, 32);
            float2 f = __half22float2(feat2[(long)s * 32 + c]);
            ax += f.x;
            ay += f.y;
        }
    }
    if (e < eend) {                                    // exactly 16 remain
        int i0 = srcs[e + hi * 8 + (c & 7)];
#pragma unroll
        for (int j = 0; j < 8; ++j) {
            int s = __shfl(i0, j, 32);
            float2 f = __half22float2(feat2[(long)s * 32 + c]);
            ax += f.x;
            ay += f.y;
        }
    }
    ax += __shfl_xor(ax, 32);
    ay += __shfl_xor(ay, 32);
    if (hi == 0) {
        float dn = dinv[wid];
        out[(long)wid * 32 + c] = __floats2half2_rn(ax * dn, ay * dn);
    }
}

// ---------------- BN1 stats over fp16 h1 ----------------
__global__ __launch_bounds__(256) void k_stats64h(const __half2* __restrict__ h2,
                                                  float* __restrict__ sums, float* __restrict__ sqs) {
    __shared__ float sx[256], sy[256], qx[256], qy[256];
    int tid = threadIdx.x;
    int c = tid & 31, rg = tid >> 5;
    long row0 = (long)blockIdx.x * 1024;
    float ax = 0.f, ay = 0.f, bx = 0.f, by = 0.f;
    for (int i = rg; i < 1024; i += 8) {
        float2 f = __half22float2(h2[(row0 + i) * 32 + c]);
        ax += f.x; ay += f.y; bx += f.x * f.x; by += f.y * f.y;
    }
    sx[tid] = ax; sy[tid] = ay; qx[tid] = bx; qy[tid] = by;
    __syncthreads();
    if (tid < 32) {
        float tax = 0.f, tay = 0.f, tbx = 0.f, tby = 0.f;
#pragma unroll
        for (int g = 0; g < 8; ++g) {
            tax += sx[g * 32 + tid]; tay += sy[g * 32 + tid];
            tbx += qx[g * 32 + tid]; tby += qy[g * 32 + tid];
        }
        atomicAdd(&sums[2 * tid], tax); atomicAdd(&sums[2 * tid + 1], tay);
        atomicAdd(&sqs[2 * tid], tbx);  atomicAdd(&sqs[2 * tid + 1], tby);
    }
}

// BN1 prep (inlined per block) + apply + leaky + dinv[row] pre-scale, fp16 in/out
__global__ __launch_bounds__(256) void k_apply1h(const __half* __restrict__ h,
                                                 const float* __restrict__ sums,
                                                 const float* __restrict__ sqs,
                                                 const float* __restrict__ gamma,
                                                 const float* __restrict__ beta,
                                                 const float* __restrict__ dinv,
                                                 __half* __restrict__ out) {
    __shared__ float sc_[64], sh_[64];
    int tid = threadIdx.x;
    if (tid < 64) {
        const float invN = 1.0f / (float)NN;
        float mean = sums[tid] * invN;
        float var = sqs[tid] * invN - mean * mean;
        float inv = rsqrtf(var + EPSV);
        float s = gamma[tid] * inv;
        sc_[tid] = s;
        sh_[tid] = beta[tid] - mean * s;
    }
    __syncthreads();
    long idx = (long)blockIdx.x * 256 + tid;           // unit: 8 halves
    int row = (int)(idx >> 3);
    int cb = (int)(idx & 7) * 8;
    float dv = dinv[row];
    int4 v = ((const int4*)h)[idx];
    __half2* hp = (__half2*)&v;
    int4 o;
    __half2* op = (__half2*)&o;
#pragma unroll
    for (int j = 0; j < 4; ++j) {
        float2 f = __half22float2(hp[j]);
        float y0 = fmaf(f.x, sc_[cb + 2 * j], sh_[cb + 2 * j]);
        float y1 = fmaf(f.y, sc_[cb + 2 * j + 1], sh_[cb + 2 * j + 1]);
        y0 = y0 > 0.f ? y0 : 0.01f * y0;
        y1 = y1 > 0.f ? y1 : 0.01f * y1;
        op[j] = __floats2half2_rn(y0 * dv, y1 * dv);
    }
    ((int4*)out)[idx] = o;
}

// ---------------- pooling: BN2 prep (inlined) + graph range search (inlined) + BN2+leaky + head ----------------
__global__ __launch_bounds__(256) void k_pool(const __half* __restrict__ h,
                                              const int* __restrict__ batch,
                                              const float* __restrict__ sums,
                                              const float* __restrict__ sqs,
                                              const float* __restrict__ gamma,
                                              const float* __restrict__ beta,
                                              const float* __restrict__ Wo,
                                              const float* __restrict__ bo,
                                              float* __restrict__ out) {
    __shared__ float accx[4][64], accy[4][64];
    __shared__ float sc_[128], sh_[128];
    __shared__ int range[2];
    int g = blockIdx.x;
    int tid = threadIdx.x;
    int wv = tid >> 6, lane = tid & 63;
    if (tid < 128) {
        const float invN = 1.0f / (float)NN;
        float mean = sums[tid] * invN;
        float var = sqs[tid] * invN - mean * mean;
        float inv = rsqrtf(var + EPSV);
        float s = gamma[tid] * inv;
        sc_[tid] = s;
        sh_[tid] = beta[tid] - mean * s;
    }
    if (tid < 2) {                                     // binary search for lower bounds of g and g+1
        int target = g + tid;
        int lo = 0, hi = NN;
        while (lo < hi) {
            int mid = (lo + hi) >> 1;
            if (batch[mid] < target) lo = mid + 1; else hi = mid;
        }
        range[tid] = lo;
    }
    __syncthreads();
    int beg = range[0], cnt = range[1] - range[0];
    float sc0 = sc_[2 * lane], sc1 = sc_[2 * lane + 1];
    float sh0 = sh_[2 * lane], sh1 = sh_[2 * lane + 1];
    float a0 = 0.f, a1 = 0.f;
    for (int i = wv; i < cnt; i += 4) {
        __half2 v = ((const __half2*)(h + (long)(beg + i) * 128))[lane];
        float2 f = __half22float2(v);
        float y0 = fmaf(f.x, sc0, sh0); y0 = y0 > 0.f ? y0 : 0.01f * y0;
        float y1 = fmaf(f.y, sc1, sh1); y1 = y1 > 0.f ? y1 : 0.01f * y1;
        a0 += y0; a1 += y1;
    }
    accx[wv][lane] = a0;
    accy[wv][lane] = a1;
    __syncthreads();
    if (wv == 0) {
        a0 = accx[0][lane] + accx[1][lane] + accx[2][lane] + accx[3][lane];
        a1 = accy[0][lane] + accy[1][lane] + accy[2][lane] + accy[3][lane];
        float v = a0 * Wo[2 * lane] + a1 * Wo[2 * lane + 1];
        v /= fmaxf((float)cnt, 1.f);
#pragma unroll
        for (int m = 32; m; m >>= 1) v += __shfl_xor(v, m);
        if (lane == 0) out[g] = v + bo[0];
    }
}

extern "C" void kernel_launch(void* const* d_in, const int* in_sizes, int n_in,
                              void* d_out, int out_size, void* d_ws, size_t ws_size,
                              hipStream_t stream) {
    const float* x    = (const float*)d_in[0];
    const int* ei     = (const int*)d_in[1];
    const int* batch  = (const int*)d_in[2];
    const float* W1   = (const float*)d_in[3];
    const float* g1   = (const float*)d_in[5];
    const float* be1  = (const float*)d_in[6];
    const float* W2   = (const float*)d_in[7];
    const float* g2   = (const float*)d_in[9];
    const float* be2  = (const float*)d_in[10];
    const float* Wo   = (const float*)d_in[11];
    const float* bo   = (const float*)d_in[12];
    float* out = (float*)d_out;

    const int* esrc = ei;
    const int* edst = ei + NE;

    // ---- workspace layout ----
    __half* h2h = (__half*)d_ws;                   // [NN,128] half (33.5MB); alias: packed
    __half* bufA = h2h + (size_t)NN * 128;         // [NN+1,64] half; alias: ghist_t/scanned
    __half* bufB = bufA + (size_t)(NN + 1) * 64;   // [NN+1,64] half
    float* dinv = (float*)(bufB + (size_t)(NN + 1) * 64); // [NN]
    float* stats = dinv + NN;                      // 1024 floats (zeroed by k_chist block 0)
    float* sums1 = stats,        *sqs1 = stats + 64;
    float* sums2 = stats + 128,  *sqs2 = stats + 256;
    int2* ninfo = (int2*)(stats + 1024);           // [NN]
    int* srcs   = (int*)(ninfo + NN);              // [NTP]
    int* bsums  = srcs + NTP;                      // 256
    int* bsums2 = bsums + 256;                     // 256
    int* dummy  = bsums2 + 256;                    // 8
    float* pS   = (float*)(dummy + 8);             // [2048][128]
    float* pQ   = pS + 2048 * 128;                 // [2048][128]
    // temporal aliases
    int* ghist_t = (int*)bufA;                     // [NB][CH]  (consumed before gemm1 writes bufA)
    int* scanned = ghist_t + NB * CH;
    int* packed  = (int*)h2h;                      // [NE]      (consumed before gemm2 writes h2h)
    __half* sentA = bufA + (size_t)NN * 64;        // sentinel rows (zeroed by k_chist)
    __half* sentB = bufB + (size_t)NN * 64;

    // ---- CSR build ----
    k_chist<<<CH, 512, 0, stream>>>(edst, ghist_t, stats, sentA, sentB);
    k_scan1<<<NB * CH / 1024, 1024, 0, stream>>>(ghist_t, scanned, bsums, NB * CH);
    k_scan1<<<1, 1024, 0, stream>>>(bsums, bsums2, dummy, NB * CH / 1024);
    k_cscatter<<<CH, 512, 0, stream>>>(esrc, edst, scanned, bsums2, packed);
    k_fine<<<NB, 1024, 0, stream>>>(packed, scanned, bsums2, ninfo, dinv, srcs);

    // layer 1: xw1' = (x @ W1) * dinv[row]  (fp16, MFMA)
    k_gemm1<<<NN / 64, 256, 0, stream>>>(x, W1, dinv, bufA);
    k_agg<<<NN / 4, 256, 0, stream>>>((const __half2*)bufA, ninfo, srcs, dinv, (__half2*)bufB);
    k_stats64h<<<NN / 1024, 256, 0, stream>>>((const __half2*)bufB, sums1, sqs1);
    k_apply1h<<<NN * 64 / 8 / 256, 256, 0, stream>>>(bufB, sums1, sqs1, g1, be1, dinv, bufB);

    // layer 2: agg in 64ch, then gemm2 (MFMA v2, +fused conflict-free BN2 stats)
    k_agg<<<NN / 4, 256, 0, stream>>>((const __half2*)bufB, ninfo, srcs, dinv, (__half2*)bufA);
    k_gemm2<<<NN / 64, 256, 0, stream>>>(bufA, W2, h2h, pS, pQ);
    k_redstats<<<64, 256, 0, stream>>>(pS, pQ, sums2, sqs2);

    // pooling (+BN2 prep + range search + leaky fused) + head: one block per graph
    k_pool<<<NG, 256, 0, stream>>>(h2h, batch, sums2, sqs2, g2, be2, Wo, bo, out);
}